// Round 5
// baseline (140.940 us; speedup 1.0000x reference)
//
#include <hip/hip_runtime.h>

// Problem constants
#define NROWS 512          // N
#define FEAT  8192         // NUM_CHANNELS*4*4
#define BDIM  64
#define CDIM  16
#define MCOLS 1024         // BDIM*CDIM
#define OUTC  8256         // FEAT + BDIM
#define KSPLIT 16
#define KCHUNK (FEAT / KSPLIT)     // 512
#define KSTEPS (KCHUNK / 64)       // 8
#define MSIZE  (NROWS * MCOLS)     // 524288 floats = 2 MB

typedef __bf16 bf16x8 __attribute__((ext_vector_type(8)));
typedef float  floatx4 __attribute__((ext_vector_type(4)));

// two fp32 -> packed bf16 pair (HW RNE)
static __device__ __forceinline__ unsigned int pk2(float a, float b) {
    unsigned short lo = __builtin_bit_cast(unsigned short, (__bf16)a);
    unsigned short hi = __builtin_bit_cast(unsigned short, (__bf16)b);
    return (unsigned int)lo | ((unsigned int)hi << 16);
}

// ---------------------------------------------------------------------------
// k_gemm: M = x@T, fused fp32->bf16 + T-transpose in staging, plus the
// x -> out[:, :8192] copy fused into the 64 blocks with nt == (ks&7) (their
// staged A-chunks tile x exactly once; stores come from the same registers).
// 128x128 tile, 512 thr (8 waves 2x4), BK=64, split-K=16, grid 512 =
// 2 blocks/CU (launch_bounds(512,4) -> 4 waves/EU). Cross-block overlap is
// the latency-hiding mechanism (R1 showed VGPR=52: the compiler sinks deep
// reg-prefetch to first use, so source pipelining alone doesn't fly).
// Double-buffered LDS, ONE raw s_barrier per K-step with lgkmcnt(0) only --
// vmcnt is never drained in-loop. Single-barrier safety: write(k) of buf
// (k&1) races only reads(k-2) of that buf, which retire before barrier(k-1)
// (each wave's lgkmcnt(0) before that barrier covers its ds_reads).
// sched_barrier(0) after the inline-asm lgkmcnt pins MFMAs below the wait
// (guide rule #18: hipcc may hoist register-only MFMA past asm waitcnt).
// ---------------------------------------------------------------------------
__global__ __launch_bounds__(512, 4) void k_gemm(const float* __restrict__ x,
                                                 const float* __restrict__ T,
                                                 float* __restrict__ Mp,
                                                 float* __restrict__ out) {
    __shared__ __align__(16) unsigned short ldsA[2][128 * 64];   // 32 KB
    __shared__ __align__(16) unsigned short ldsB[2][128 * 64];   // 32 KB
    char* ldsAc = (char*)ldsA;
    char* ldsBc = (char*)ldsB;

    int bid = blockIdx.x;
    int wg = (bid & 7) * 64 + (bid >> 3);        // XCD-contiguous remap
    int mt = wg & 3, nt = (wg >> 2) & 7, ks = wg >> 5;   // ks in 0..15
    int m0 = mt * 128, n0 = nt * 128, kbase = ks * KCHUNK;
    int t = threadIdx.x, w = t >> 6, l = t & 63;
    bool docopy = (nt == (ks & 7));              // 64 blocks tile x once

    // ---- staging geometry: A rows (k-contiguous, no transpose)
    int arow = t >> 4, aq = t & 15;              // 32 rows (+r*32), 16 k-quads
    const float* gA = x + (size_t)(m0 + arow) * FEAT + kbase + aq * 4;
    float* gC = out + (size_t)(m0 + arow) * OUTC + kbase + aq * 4;
    int swa = (arow & 7) ^ ((arow >> 2) & 7);    // invariant under +32 rows
    int wA = arow * 128 + (((aq >> 1) ^ swa) << 4) + ((aq & 1) << 3);

    // ---- staging geometry: B (transpose T[k][n] -> n-major rows)
    int n4 = t & 31, kg = t >> 5;                // 32 n-quads, 16 k-quads
    const float* gB = T + (size_t)(kbase + kg * 4) * MCOLS + n0 + n4 * 4;
    int wB[4];
#pragma unroll
    for (int j = 0; j < 4; ++j) {
        int n = n4 * 4 + j;
        int swn = (n & 7) ^ ((n >> 2) & 7);
        wB[j] = n * 128 + (((kg >> 1) ^ swn) << 4) + ((kg & 1) << 3);
    }

    // ---- compute geometry: wave (wr=w>>2, wc=w&3) owns 64x32 of C
    int wr = w >> 2, wc = w & 3, fm = l & 15, fq = l >> 4;
    int swf = (fm & 7) ^ ((fm >> 2) & 7);
    int baseA = (wr * 64 + fm) * 128 + ((fq ^ swf) << 4);
    int baseB = (wc * 32 + fm) * 128 + ((fq ^ swf) << 4);

    floatx4 acc[4][2] = {};
    float4 va[4], vb[4];

    auto issue = [&](int KK) {
        const float* pa = gA + KK * 64;
        va[0] = *(const float4*)(pa);
        va[1] = *(const float4*)(pa + 32 * FEAT);
        va[2] = *(const float4*)(pa + 64 * FEAT);
        va[3] = *(const float4*)(pa + 96 * FEAT);
        const float* pb = gB + (size_t)KK * 64 * MCOLS;
        vb[0] = *(const float4*)(pb);
        vb[1] = *(const float4*)(pb + MCOLS);
        vb[2] = *(const float4*)(pb + 2 * MCOLS);
        vb[3] = *(const float4*)(pb + 3 * MCOLS);
    };

    issue(0);
    for (int kk = 0; kk < KSTEPS; ++kk) {
        int SO = (kk & 1) << 14;                 // 16384-byte buffer select
        // cvt + LDS write (first va/vb use waits this set's vmcnt)
#pragma unroll
        for (int r = 0; r < 4; ++r) {
            uint2 u; u.x = pk2(va[r].x, va[r].y); u.y = pk2(va[r].z, va[r].w);
            *(uint2*)(ldsAc + SO + wA + r * 4096) = u;
        }
        {
            uint2 u;
            u.x = pk2(vb[0].x, vb[1].x); u.y = pk2(vb[2].x, vb[3].x);
            *(uint2*)(ldsBc + SO + wB[0]) = u;
            u.x = pk2(vb[0].y, vb[1].y); u.y = pk2(vb[2].y, vb[3].y);
            *(uint2*)(ldsBc + SO + wB[1]) = u;
            u.x = pk2(vb[0].z, vb[1].z); u.y = pk2(vb[2].z, vb[3].z);
            *(uint2*)(ldsBc + SO + wB[2]) = u;
            u.x = pk2(vb[0].w, vb[1].w); u.y = pk2(vb[2].w, vb[3].w);
            *(uint2*)(ldsBc + SO + wB[3]) = u;
        }
        // fused x->out copy from the same registers (block-uniform branch)
        if (docopy) {
#pragma unroll
            for (int r = 0; r < 4; ++r)
                *(float4*)(gC + (size_t)r * 32 * OUTC + kk * 64) = va[r];
        }
        // prefetch next step (stores above don't block: vmcnt never drained)
        if (kk + 1 < KSTEPS) issue(kk + 1);
        asm volatile("s_waitcnt lgkmcnt(0)" ::: "memory");   // LDS only
        __builtin_amdgcn_sched_barrier(0);       // pin MFMAs below the wait
        __builtin_amdgcn_s_barrier();
        // MFMA phase reading buffer SO
#pragma unroll
        for (int h = 0; h < 2; ++h) {
            bf16x8 af[4], bfr[2];
#pragma unroll
            for (int a = 0; a < 4; ++a)
                af[a] = *(const bf16x8*)(ldsAc + SO + ((baseA + a * 2048) ^ ((h ^ (a & 1)) << 6)));
#pragma unroll
            for (int b = 0; b < 2; ++b)
                bfr[b] = *(const bf16x8*)(ldsBc + SO + ((baseB + b * 2048) ^ ((h ^ (b & 1)) << 6)));
#pragma unroll
            for (int a = 0; a < 4; ++a)
#pragma unroll
                for (int b = 0; b < 2; ++b)
                    acc[a][b] = __builtin_amdgcn_mfma_f32_16x16x32_bf16(af[a], bfr[b], acc[a][b], 0, 0, 0);
        }
    }

    // epilogue: D layout col = fm, row = fq*4 + r
    float* outp = Mp + (size_t)ks * MSIZE;
    int gr0 = m0 + wr * 64, gc0 = n0 + wc * 32;
#pragma unroll
    for (int a = 0; a < 4; ++a)
#pragma unroll
        for (int r = 0; r < 4; ++r) {
            int row = gr0 + a * 16 + fq * 4 + r;
#pragma unroll
            for (int b = 0; b < 2; ++b)
                outp[(size_t)row * MCOLS + gc0 + b * 16 + fm] = acc[a][b][r];
        }
}

// ---------------------------------------------------------------------------
// k_pair: o[i,b] = sum_j exp(-L1(M_i,M_j)) -> out[:, 8192:8256].
// Copy moved to k_gemm, so no vmcnt-drain serialization here: stage the
// split-K-reduced M into LDS, one barrier, VALU-bound pairwise loop.
// ---------------------------------------------------------------------------
__global__ __launch_bounds__(512, 1) void k_pair(const float* __restrict__ Mp,
                                                 float* __restrict__ out) {
    __shared__ float ldsM[NROWS * 20];                  // 40960 B, padded rows
    __shared__ float partial[8][64];
    int bid = blockIdx.x, t = threadIdx.x;
    int b = bid & 63, itp = bid >> 6;

#pragma unroll
    for (int p = 0; p < 4; ++p) {
        int idx = t + p * 512;                // 2048 float4 total
        int j = idx >> 2, c4 = idx & 3;
        const float* base = Mp + (size_t)j * MCOLS + b * CDIM + c4 * 4;
        float4 s = *(const float4*)base;
#pragma unroll
        for (int k = 1; k < KSPLIT; ++k) {
            float4 v = *(const float4*)(base + (size_t)k * MSIZE);
            s.x += v.x; s.y += v.y; s.z += v.z; s.w += v.w;
        }
        *(float4*)&ldsM[j * 20 + c4 * 4] = s;
    }
    __syncthreads();

    int lane = t & 63, w = t >> 6, g = t >> 8, wg = (t >> 6) & 3;
    int i = (itp * 2 + g) * 64 + lane;
    float mi[CDIM];
#pragma unroll
    for (int cc = 0; cc < CDIM; ++cc) mi[cc] = ldsM[i * 20 + cc];

    float acc = 0.0f;
    for (int jj = wg * 128; jj < wg * 128 + 128; ++jj) {
        float d = 0.0f;
#pragma unroll
        for (int cc = 0; cc < CDIM; ++cc) d += fabsf(mi[cc] - ldsM[jj * 20 + cc]);
        acc += __expf(-d);
    }
    partial[w][lane] = acc;
    __syncthreads();
    if ((t & 255) < 64) {
        int ii = (itp * 2 + g) * 64 + (t & 63);
        float o = partial[g * 4 + 0][t & 63] + partial[g * 4 + 1][t & 63] +
                  partial[g * 4 + 2][t & 63] + partial[g * 4 + 3][t & 63];
        out[(size_t)ii * OUTC + FEAT + b] = o;
    }
}

// ---------------------------------------------------------------------------
extern "C" void kernel_launch(void* const* d_in, const int* in_sizes, int n_in,
                              void* d_out, int out_size, void* d_ws, size_t ws_size,
                              hipStream_t stream) {
    const float* x = (const float*)d_in[0];      // (512, 8192)
    const float* T = (const float*)d_in[1];      // (8192, 1024)
    float* out = (float*)d_out;                  // (512, 8256)

    // ws layout: Mp 16 x 2MB = 32 MB at offset 0
    float* Mp = (float*)d_ws;

    k_gemm<<<512, 512, 0, stream>>>(x, T, Mp, out);
    k_pair<<<256, 512, 0, stream>>>(Mp, out);
}

// Round 6
// 129.611 us; speedup vs baseline: 1.0874x; 1.0874x over previous
//
#include <hip/hip_runtime.h>

// Problem constants
#define NROWS 512          // N
#define FEAT  8192         // NUM_CHANNELS*4*4
#define BDIM  64
#define CDIM  16
#define MCOLS 1024         // BDIM*CDIM
#define OUTC  8256         // FEAT + BDIM
#define KSPLIT 8
#define KCHUNK (FEAT / KSPLIT)     // 1024
#define KSTEPS (KCHUNK / 64)       // 16
#define MSIZE  (NROWS * MCOLS)     // 524288 floats = 2 MB

typedef __bf16 bf16x8 __attribute__((ext_vector_type(8)));
typedef float  floatx4 __attribute__((ext_vector_type(4)));

// two fp32 -> packed bf16 pair (HW RNE)
static __device__ __forceinline__ unsigned int pk2(float a, float b) {
    unsigned short lo = __builtin_bit_cast(unsigned short, (__bf16)a);
    unsigned short hi = __builtin_bit_cast(unsigned short, (__bf16)b);
    return (unsigned int)lo | ((unsigned int)hi << 16);
}

// ---------------------------------------------------------------------------
// k_gemm: M = x@T, fused fp32->bf16 + T-transpose in staging, plus the
// x -> out[:, :8192] copy fused into the 32 blocks with nt == ks (their
// staged A-chunks tile x exactly once; stores come from the same registers).
// R2-measured geometry restored (R5's KSPLIT=16/grid-512 regressed 10.6 us):
// 128x128 tile, 512 thr (8 waves 2x4), BK=64, split-K=8, grid 256,
// launch_bounds(512,2) (no 128-VGPR cap -> prefetch regs stay live).
// Double-buffered LDS, ONE raw s_barrier per K-step with lgkmcnt(0) only --
// vmcnt is never drained in-loop. Single-barrier safety: write(k) of buf
// (k&1) races only reads(k-2) of that buf, which retire before barrier(k-1)
// (each wave's lgkmcnt(0) before that barrier covers its ds_reads).
// sched_barrier(0) after the inline-asm lgkmcnt pins MFMAs below the wait
// (guide rule #18).
// ---------------------------------------------------------------------------
__global__ __launch_bounds__(512, 2) void k_gemm(const float* __restrict__ x,
                                                 const float* __restrict__ T,
                                                 float* __restrict__ Mp,
                                                 float* __restrict__ out) {
    __shared__ __align__(16) unsigned short ldsA[2][128 * 64];   // 32 KB
    __shared__ __align__(16) unsigned short ldsB[2][128 * 64];   // 32 KB
    char* ldsAc = (char*)ldsA;
    char* ldsBc = (char*)ldsB;

    int bid = blockIdx.x;
    int wg = (bid & 7) * 32 + (bid >> 3);        // XCD-contiguous remap
    int mt = wg & 3, nt = (wg >> 2) & 7, ks = wg >> 5;   // ks in 0..7
    int m0 = mt * 128, n0 = nt * 128, kbase = ks * KCHUNK;
    int t = threadIdx.x, w = t >> 6, l = t & 63;
    bool docopy = (nt == ks);                    // 32 blocks tile x once

    // ---- staging geometry: A rows (k-contiguous, no transpose)
    int arow = t >> 4, aq = t & 15;              // 32 rows (+r*32), 16 k-quads
    const float* gA = x + (size_t)(m0 + arow) * FEAT + kbase + aq * 4;
    float* gC = out + (size_t)(m0 + arow) * OUTC + kbase + aq * 4;
    int swa = (arow & 7) ^ ((arow >> 2) & 7);    // invariant under +32 rows
    int wA = arow * 128 + (((aq >> 1) ^ swa) << 4) + ((aq & 1) << 3);

    // ---- staging geometry: B (transpose T[k][n] -> n-major rows)
    int n4 = t & 31, kg = t >> 5;                // 32 n-quads, 16 k-quads
    const float* gB = T + (size_t)(kbase + kg * 4) * MCOLS + n0 + n4 * 4;
    int wB[4];
#pragma unroll
    for (int j = 0; j < 4; ++j) {
        int n = n4 * 4 + j;
        int swn = (n & 7) ^ ((n >> 2) & 7);
        wB[j] = n * 128 + (((kg >> 1) ^ swn) << 4) + ((kg & 1) << 3);
    }

    // ---- compute geometry: wave (wr=w>>2, wc=w&3) owns 64x32 of C
    int wr = w >> 2, wc = w & 3, fm = l & 15, fq = l >> 4;
    int swf = (fm & 7) ^ ((fm >> 2) & 7);
    int baseA = (wr * 64 + fm) * 128 + ((fq ^ swf) << 4);
    int baseB = (wc * 32 + fm) * 128 + ((fq ^ swf) << 4);

    floatx4 acc[4][2] = {};
    float4 va[4], vb[4];

    auto issue = [&](int KK) {
        const float* pa = gA + KK * 64;
        va[0] = *(const float4*)(pa);
        va[1] = *(const float4*)(pa + 32 * FEAT);
        va[2] = *(const float4*)(pa + 64 * FEAT);
        va[3] = *(const float4*)(pa + 96 * FEAT);
        const float* pb = gB + (size_t)KK * 64 * MCOLS;
        vb[0] = *(const float4*)(pb);
        vb[1] = *(const float4*)(pb + MCOLS);
        vb[2] = *(const float4*)(pb + 2 * MCOLS);
        vb[3] = *(const float4*)(pb + 3 * MCOLS);
    };

    issue(0);
    for (int kk = 0; kk < KSTEPS; ++kk) {
        int SO = (kk & 1) << 14;                 // 16384-byte buffer select
        // cvt + LDS write (first va/vb use waits this set's vmcnt)
#pragma unroll
        for (int r = 0; r < 4; ++r) {
            uint2 u; u.x = pk2(va[r].x, va[r].y); u.y = pk2(va[r].z, va[r].w);
            *(uint2*)(ldsAc + SO + wA + r * 4096) = u;
        }
        {
            uint2 u;
            u.x = pk2(vb[0].x, vb[1].x); u.y = pk2(vb[2].x, vb[3].x);
            *(uint2*)(ldsBc + SO + wB[0]) = u;
            u.x = pk2(vb[0].y, vb[1].y); u.y = pk2(vb[2].y, vb[3].y);
            *(uint2*)(ldsBc + SO + wB[1]) = u;
            u.x = pk2(vb[0].z, vb[1].z); u.y = pk2(vb[2].z, vb[3].z);
            *(uint2*)(ldsBc + SO + wB[2]) = u;
            u.x = pk2(vb[0].w, vb[1].w); u.y = pk2(vb[2].w, vb[3].w);
            *(uint2*)(ldsBc + SO + wB[3]) = u;
        }
        // fused x->out copy from the same registers (block-uniform branch)
        if (docopy) {
#pragma unroll
            for (int r = 0; r < 4; ++r)
                *(float4*)(gC + (size_t)r * 32 * OUTC + kk * 64) = va[r];
        }
        // prefetch next step (stores above don't block: vmcnt never drained)
        if (kk + 1 < KSTEPS) issue(kk + 1);
        asm volatile("s_waitcnt lgkmcnt(0)" ::: "memory");   // LDS only
        __builtin_amdgcn_sched_barrier(0);       // pin MFMAs below the wait
        __builtin_amdgcn_s_barrier();
        // MFMA phase reading buffer SO
#pragma unroll
        for (int h = 0; h < 2; ++h) {
            bf16x8 af[4], bfr[2];
#pragma unroll
            for (int a = 0; a < 4; ++a)
                af[a] = *(const bf16x8*)(ldsAc + SO + ((baseA + a * 2048) ^ ((h ^ (a & 1)) << 6)));
#pragma unroll
            for (int b = 0; b < 2; ++b)
                bfr[b] = *(const bf16x8*)(ldsBc + SO + ((baseB + b * 2048) ^ ((h ^ (b & 1)) << 6)));
#pragma unroll
            for (int a = 0; a < 4; ++a)
#pragma unroll
                for (int b = 0; b < 2; ++b)
                    acc[a][b] = __builtin_amdgcn_mfma_f32_16x16x32_bf16(af[a], bfr[b], acc[a][b], 0, 0, 0);
        }
    }

    // epilogue: D layout col = fm, row = fq*4 + r
    float* outp = Mp + (size_t)ks * MSIZE;
    int gr0 = m0 + wr * 64, gc0 = n0 + wc * 32;
#pragma unroll
    for (int a = 0; a < 4; ++a)
#pragma unroll
        for (int r = 0; r < 4; ++r) {
            int row = gr0 + a * 16 + fq * 4 + r;
#pragma unroll
            for (int b = 0; b < 2; ++b)
                outp[(size_t)row * MCOLS + gc0 + b * 16 + fm] = acc[a][b][r];
        }
}

// ---------------------------------------------------------------------------
// k_pair: o[i,b] = sum_j exp(-L1(M_i,M_j)) -> out[:, 8192:8256].
// Copy lives in k_gemm, so no vmcnt-drain serialization here. Inner loop
// reads ldsM rows as float4 (ds_read_b128, ~2x LDS-pipe cycles saved vs
// 16x ds_read_b32); jj is wave-uniform -> broadcast, conflict-free.
// ---------------------------------------------------------------------------
__global__ __launch_bounds__(512, 1) void k_pair(const float* __restrict__ Mp,
                                                 float* __restrict__ out) {
    __shared__ __align__(16) float ldsM[NROWS * 20];    // 40960 B, padded rows
    __shared__ float partial[8][64];
    int bid = blockIdx.x, t = threadIdx.x;
    int b = bid & 63, itp = bid >> 6;

#pragma unroll
    for (int p = 0; p < 4; ++p) {
        int idx = t + p * 512;                // 2048 float4 total
        int j = idx >> 2, c4 = idx & 3;
        const float* base = Mp + (size_t)j * MCOLS + b * CDIM + c4 * 4;
        float4 s = *(const float4*)base;
#pragma unroll
        for (int k = 1; k < KSPLIT; ++k) {
            float4 v = *(const float4*)(base + (size_t)k * MSIZE);
            s.x += v.x; s.y += v.y; s.z += v.z; s.w += v.w;
        }
        *(float4*)&ldsM[j * 20 + c4 * 4] = s;
    }
    __syncthreads();

    int lane = t & 63, w = t >> 6, g = t >> 8, wg = (t >> 6) & 3;
    int i = (itp * 2 + g) * 64 + lane;
    float4 mi0 = *(const float4*)&ldsM[i * 20 + 0];
    float4 mi1 = *(const float4*)&ldsM[i * 20 + 4];
    float4 mi2 = *(const float4*)&ldsM[i * 20 + 8];
    float4 mi3 = *(const float4*)&ldsM[i * 20 + 12];

    float acc = 0.0f;
    for (int jj = wg * 128; jj < wg * 128 + 128; ++jj) {
        const float4* rp = (const float4*)&ldsM[jj * 20];
        float4 a0 = rp[0], a1 = rp[1], a2 = rp[2], a3 = rp[3];
        float d = fabsf(mi0.x - a0.x) + fabsf(mi0.y - a0.y)
                + fabsf(mi0.z - a0.z) + fabsf(mi0.w - a0.w)
                + fabsf(mi1.x - a1.x) + fabsf(mi1.y - a1.y)
                + fabsf(mi1.z - a1.z) + fabsf(mi1.w - a1.w)
                + fabsf(mi2.x - a2.x) + fabsf(mi2.y - a2.y)
                + fabsf(mi2.z - a2.z) + fabsf(mi2.w - a2.w)
                + fabsf(mi3.x - a3.x) + fabsf(mi3.y - a3.y)
                + fabsf(mi3.z - a3.z) + fabsf(mi3.w - a3.w);
        acc += __expf(-d);
    }
    partial[w][lane] = acc;
    __syncthreads();
    if ((t & 255) < 64) {
        int ii = (itp * 2 + g) * 64 + (t & 63);
        float o = partial[g * 4 + 0][t & 63] + partial[g * 4 + 1][t & 63] +
                  partial[g * 4 + 2][t & 63] + partial[g * 4 + 3][t & 63];
        out[(size_t)ii * OUTC + FEAT + b] = o;
    }
}

// ---------------------------------------------------------------------------
extern "C" void kernel_launch(void* const* d_in, const int* in_sizes, int n_in,
                              void* d_out, int out_size, void* d_ws, size_t ws_size,
                              hipStream_t stream) {
    const float* x = (const float*)d_in[0];      // (512, 8192)
    const float* T = (const float*)d_in[1];      // (8192, 1024)
    float* out = (float*)d_out;                  // (512, 8256)

    // ws layout: Mp 8 x 2MB = 16 MB at offset 0
    float* Mp = (float*)d_ws;

    k_gemm<<<256, 512, 0, stream>>>(x, T, Mp, out);
    k_pair<<<256, 512, 0, stream>>>(Mp, out);
}